// Round 7
// baseline (770.698 us; speedup 1.0000x reference)
//
#include <hip/hip_runtime.h>
#include <math.h>

// ---------------------------------------------------------------------------
// SwinTransformerBlock3D  (B=2, D=16, H=56, W=56, C=256, heads=8, ws=4, ss=2)
// f32 in / f32 out. M = 100352 rows, 1568 windows. 6 launches:
//   transpose_all -> ln1qkv (fused LN1+roll+partition+qkv GEMM) -> attention
//   -> projln2 (proj GEMM + reverse+roll+resid + fused LN2) -> fc1 -> fc2
// Round 4 (WIN 734->706): LDS-bounce epilogue. Round 5: mlp_k fusion failed
//   (barrier-drain serialization). Round 6 (WIN 706->667): 2-phase dbuf gemm.
// Round 7: window-level fusion with small-barrier-count blocks:
//   ln1qkv_k: x (rolled, f32, kept in regs for LN) -> Xn LDS 32KB -> 8 waves
//     x 64x96 qkv slices (W from L2) -> LDS bounce -> coalesced bufL write.
//   projln2_k: ao staged 32KB -> proj MFMA (W L2) -> Cs f32 64KB bounce ->
//     +resid(x rolled) -> x1 + fused LN2 -> yn (separate bufY).
// GEMM (fc1/fc2): 2-phase dbuf, BK=64, glds16 + XOR swizzle, LDS-bounce epi.
// ---------------------------------------------------------------------------

using f32x4  = __attribute__((ext_vector_type(4))) float;
using bf16x8 = __attribute__((ext_vector_type(8))) short;

#define MFMA16 __builtin_amdgcn_mfma_f32_16x16x32_bf16

__device__ __forceinline__ short f2bf(float f) {
  unsigned u = __builtin_bit_cast(unsigned, f);
  u += 0x7fffu + ((u >> 16) & 1u);          // RNE
  return (short)(u >> 16);
}

__device__ __forceinline__ float gelu_f(float v) {
  const float u = 1.5957691216057308f * v * (1.f + 0.044715f * v * v);
  const float e = __expf(u);
  return v - v * __builtin_amdgcn_rcpf(e + 1.f);
}

#define GLDS16(g, l) __builtin_amdgcn_global_load_lds(                        \
    (__attribute__((address_space(1))) void*)(g),                             \
    (__attribute__((address_space(3))) void*)(l), 16, 0, 0)

// rolled-gather mapping (verified in ln1_part_k since round 0)
__device__ __forceinline__ size_t swin_src(int win, int tok) {
  const int b = win / 784, wi = win % 784;
  const int wd = wi / 196, wh = (wi / 14) % 14, ww = wi % 14;
  const int tz = tok >> 4, ty = (tok >> 2) & 3, tx = tok & 3;
  const int gd = (wd * 4 + tz + 2) & 15;
  int gh = wh * 4 + ty + 2; if (gh >= 56) gh -= 56;
  int gw = ww * 4 + tx + 2; if (gw >= 56) gw -= 56;
  return ((((size_t)b * 16 + gd) * 56 + gh) * 56 + gw) * 256;
}

// ---------------------------------------------------------------------------
// all four weight transposes in one launch: [K][N] f32 -> [N][K] bf16
__global__ void transpose_all_k(const float* __restrict__ qkv_w,
                                const float* __restrict__ proj_w,
                                const float* __restrict__ fc1_w,
                                const float* __restrict__ fc2_w,
                                short* __restrict__ o_qkv,
                                short* __restrict__ o_proj,
                                short* __restrict__ o_fc1,
                                short* __restrict__ o_fc2) {
  int bid = blockIdx.x;
  const float* in; short* out; int K, N;
  if (bid < 768)       { in = qkv_w;  out = o_qkv;  K = 256;  N = 768; }
  else if (bid < 1024) { in = proj_w; out = o_proj; K = 256;  N = 256;  bid -= 768; }
  else if (bid < 2048) { in = fc1_w;  out = o_fc1;  K = 256;  N = 1024; bid -= 1024; }
  else                 { in = fc2_w;  out = o_fc2;  K = 1024; N = 256;  bid -= 2048; }
  const int idx = bid * 256 + threadIdx.x;
  const int k = idx / N, n = idx % N;
  out[(size_t)n * K + k] = f2bf(in[idx]);
}

// ---------------------------------------------------------------------------
// Fused LN1 + roll + window partition + qkv GEMM.  1 block = 1 window.
// 512 threads = 8 waves; wave h computes head h's 64x96 qkv slice.
// LDS 32KB: Xn [64][256] bf16 (chunk ^ row&7 swizzle), reused as bounce Cs.
__global__ __launch_bounds__(512) void ln1qkv_k(
    const float* __restrict__ x, const float* __restrict__ g,
    const float* __restrict__ bta, const short* __restrict__ Wq,  // [768][256]
    const float* __restrict__ qb, short* __restrict__ qkv) {
  __shared__ __align__(16) char SM[32768];
  const int tid = threadIdx.x;
  const int win = blockIdx.x;

  // ---- phase A: LN1 (8 lanes per token)
  {
    const int tk = tid >> 3, lane3 = tid & 7;
    const size_t src = swin_src(win, tk);
    f32x4 xr[8];
#pragma unroll
    for (int i = 0; i < 8; ++i)
      xr[i] = *(const f32x4*)(x + src + lane3 * 32 + i * 4);
    float s = 0.f;
#pragma unroll
    for (int i = 0; i < 8; ++i) s += xr[i][0] + xr[i][1] + xr[i][2] + xr[i][3];
    s += __shfl_xor(s, 1); s += __shfl_xor(s, 2); s += __shfl_xor(s, 4);
    const float mean = s * (1.f / 256.f);
    float q = 0.f;
#pragma unroll
    for (int i = 0; i < 8; ++i)
#pragma unroll
      for (int j = 0; j < 4; ++j) {
        const float d = xr[i][j] - mean; q += d * d;
      }
    q += __shfl_xor(q, 1); q += __shfl_xor(q, 2); q += __shfl_xor(q, 4);
    const float rstd = rsqrtf(q * (1.f / 256.f) + 1e-5f);
#pragma unroll
    for (int cc = 0; cc < 4; ++cc) {
      const float4 g0 = *(const float4*)(g + lane3 * 32 + cc * 8);
      const float4 g1 = *(const float4*)(g + lane3 * 32 + cc * 8 + 4);
      const float4 b0 = *(const float4*)(bta + lane3 * 32 + cc * 8);
      const float4 b1 = *(const float4*)(bta + lane3 * 32 + cc * 8 + 4);
      const f32x4 va = xr[cc * 2], vb = xr[cc * 2 + 1];
      bf16x8 o;
      o[0] = f2bf((va[0] - mean) * rstd * g0.x + b0.x);
      o[1] = f2bf((va[1] - mean) * rstd * g0.y + b0.y);
      o[2] = f2bf((va[2] - mean) * rstd * g0.z + b0.z);
      o[3] = f2bf((va[3] - mean) * rstd * g0.w + b0.w);
      o[4] = f2bf((vb[0] - mean) * rstd * g1.x + b1.x);
      o[5] = f2bf((vb[1] - mean) * rstd * g1.y + b1.y);
      o[6] = f2bf((vb[2] - mean) * rstd * g1.z + b1.z);
      o[7] = f2bf((vb[3] - mean) * rstd * g1.w + b1.w);
      const int byte = tk * 512 + (((lane3 * 4 + cc) ^ (tk & 7)) << 4);
      *(bf16x8*)(SM + byte) = o;
    }
  }
  __syncthreads();

  // ---- phase B: qkv MFMA (wave = head)
  const int wave = tid >> 6, lane = tid & 63;
  const int quad = lane >> 4, l15 = lane & 15;
  const int h = wave;
  f32x4 acc[3][2][4] = {};
#pragma unroll
  for (int kk = 0; kk < 8; ++kk) {
    bf16x8 af[4];
#pragma unroll
    for (int mt = 0; mt < 4; ++mt) {
      const int t = mt * 16 + l15;
      const int byte = t * 512 + (((kk * 4 + quad) ^ (t & 7)) << 4);
      af[mt] = *(const bf16x8*)(SM + byte);
    }
#pragma unroll
    for (int gq = 0; gq < 3; ++gq)
#pragma unroll
      for (int ct = 0; ct < 2; ++ct) {
        const int col = gq * 256 + h * 32 + ct * 16 + l15;
        const bf16x8 bfr =
            *(const bf16x8*)(Wq + (size_t)col * 256 + kk * 32 + quad * 8);
#pragma unroll
        for (int mt = 0; mt < 4; ++mt)
          acc[gq][ct][mt] = MFMA16(af[mt], bfr, acc[gq][ct][mt], 0, 0, 0);
      }
  }

  // ---- phase C: bounce each 256-col plane through LDS, coalesced write
  short* const outp = qkv + (size_t)win * 64 * 768;
#pragma unroll
  for (int gq = 0; gq < 3; ++gq) {
    __syncthreads();                      // prior readers of SM done
#pragma unroll
    for (int ct = 0; ct < 2; ++ct)
#pragma unroll
      for (int mt = 0; mt < 4; ++mt)
#pragma unroll
        for (int reg = 0; reg < 4; ++reg) {
          const int t = mt * 16 + quad * 4 + reg;
          const int col = h * 32 + ct * 16 + l15;
          const float v = acc[gq][ct][mt][reg] + qb[gq * 256 + col];
          const int cb = col * 2;
          const int byte = t * 512 + (((cb >> 4) ^ (t & 7)) << 4) + (cb & 15);
          *(short*)(SM + byte) = f2bf(v);
        }
    __syncthreads();
#pragma unroll
    for (int i = 0; i < 4; ++i) {
      const int off = i * 8192 + tid * 16;
      const int row = off >> 9, cb = off & 511;
      const bf16x8 val = *(const bf16x8*)(SM + (off ^ ((row & 7) << 4)));
      *(bf16x8*)(outp + (size_t)row * 768 + gq * 256 + (cb >> 1)) = val;
    }
  }
}

// ---------------------------------------------------------------------------
// Fused proj GEMM + window-reverse + roll + residual + LN2. 1 block = 64 rows.
// 256 threads = 4 waves; wave w owns out cols w*64..w*64+64 (all 64 tokens).
// LDS 64KB: As [64][256] bf16 32KB (staged), reused as Cs f32 [64][256] 64KB.
__global__ __launch_bounds__(256) void projln2_k(
    const short* __restrict__ ao, const short* __restrict__ Wp,  // [256][256]
    const float* __restrict__ pb, const float* __restrict__ xres,
    const float* __restrict__ g2, const float* __restrict__ b2,
    float* __restrict__ x1, short* __restrict__ yn) {
  __shared__ __align__(16) char SM[65536];
  const int tid = threadIdx.x;
  const int wave = tid >> 6, lane = tid & 63;
  const int quad = lane >> 4, l15 = lane & 15;
  const int m0 = blockIdx.x * 64;

  // stage As [64][256] bf16 with chunk^row&7 swizzle (32 chunks/row)
#pragma unroll
  for (int i = 0; i < 8; ++i) {
    const int p = i * 256 + tid;
    const int row = p >> 5;
    const int c = (p & 31) ^ (row & 7);
    GLDS16(ao + (size_t)(m0 + row) * 256 + c * 8, SM + p * 16);
  }
  __syncthreads();

  f32x4 pacc[4][4] = {};
#pragma unroll
  for (int kk = 0; kk < 8; ++kk) {
    bf16x8 af[4];
#pragma unroll
    for (int mt = 0; mt < 4; ++mt) {
      const int t = mt * 16 + l15;
      const int byte = t * 512 + (((kk * 4 + quad) ^ (t & 7)) << 4);
      af[mt] = *(const bf16x8*)(SM + byte);
    }
#pragma unroll
    for (int nt = 0; nt < 4; ++nt) {
      const int col = wave * 64 + nt * 16 + l15;
      const bf16x8 bfr =
          *(const bf16x8*)(Wp + (size_t)col * 256 + kk * 32 + quad * 8);
#pragma unroll
      for (int mt = 0; mt < 4; ++mt)
        pacc[mt][nt] = MFMA16(af[mt], bfr, pacc[mt][nt], 0, 0, 0);
    }
  }

  // bounce to Cs f32 [64][256] (64 chunks/row, chunk^row&7)
  __syncthreads();
#pragma unroll
  for (int nt = 0; nt < 4; ++nt) {
    const int col = wave * 64 + nt * 16 + l15;
    const float bv = pb[col];
#pragma unroll
    for (int mt = 0; mt < 4; ++mt)
#pragma unroll
      for (int reg = 0; reg < 4; ++reg) {
        const int t = mt * 16 + quad * 4 + reg;
        const int byte =
            t * 1024 + ((((col >> 2)) ^ (t & 7)) << 4) + (col & 3) * 4;
        *(float*)(SM + byte) = pacc[mt][nt][reg] + bv;
      }
  }
  __syncthreads();

  // final: 4 lanes per token; +resid (rolled) -> x1, LN2 -> yn
  const int tok = tid >> 2, lane2 = tid & 3;
  const size_t src = swin_src(blockIdx.x, tok);
  f32x4 x1v[16];
  float s = 0.f;
#pragma unroll
  for (int cc = 0; cc < 16; ++cc) {
    const int ch = lane2 * 16 + cc;
    f32x4 v = *(const f32x4*)(SM + tok * 1024 + ((ch ^ (tok & 7)) << 4));
    const f32x4 r = *(const f32x4*)(xres + src + lane2 * 64 + cc * 4);
    v = v + r;
    x1v[cc] = v;
    s += v[0] + v[1] + v[2] + v[3];
  }
  s += __shfl_xor(s, 1); s += __shfl_xor(s, 2);
  const float mean = s * (1.f / 256.f);
  float q = 0.f;
#pragma unroll
  for (int cc = 0; cc < 16; ++cc)
#pragma unroll
    for (int j = 0; j < 4; ++j) {
      const float d = x1v[cc][j] - mean; q += d * d;
    }
  q += __shfl_xor(q, 1); q += __shfl_xor(q, 2);
  const float rstd = rsqrtf(q * (1.f / 256.f) + 1e-5f);
#pragma unroll
  for (int cc = 0; cc < 16; ++cc)
    *(f32x4*)(x1 + src + lane2 * 64 + cc * 4) = x1v[cc];
#pragma unroll
  for (int u = 0; u < 8; ++u) {
    const float4 gA = *(const float4*)(g2 + lane2 * 64 + u * 8);
    const float4 gB = *(const float4*)(g2 + lane2 * 64 + u * 8 + 4);
    const float4 bA = *(const float4*)(b2 + lane2 * 64 + u * 8);
    const float4 bB = *(const float4*)(b2 + lane2 * 64 + u * 8 + 4);
    const f32x4 va = x1v[u * 2], vb = x1v[u * 2 + 1];
    bf16x8 o;
    o[0] = f2bf((va[0] - mean) * rstd * gA.x + bA.x);
    o[1] = f2bf((va[1] - mean) * rstd * gA.y + bA.y);
    o[2] = f2bf((va[2] - mean) * rstd * gA.z + bA.z);
    o[3] = f2bf((va[3] - mean) * rstd * gA.w + bA.w);
    o[4] = f2bf((vb[0] - mean) * rstd * gB.x + bB.x);
    o[5] = f2bf((vb[1] - mean) * rstd * gB.y + bB.y);
    o[6] = f2bf((vb[2] - mean) * rstd * gB.z + bB.z);
    o[7] = f2bf((vb[3] - mean) * rstd * gB.w + bB.w);
    *(bf16x8*)(yn + src + lane2 * 64 + u * 8) = o;
  }
}

// ---------------------------------------------------------------------------
// bf16 MFMA GEMM (fc1/fc2): 128x128 tile, BK=64, 2-phase dbuf, LDS-bounce epi.
// EPI: 1=bf16 GELU store, 3=f32 +resid(f32) -> d_out (linear rows)
template <int EPI>
__global__ __launch_bounds__(256) void gemm_k(
    const short* __restrict__ A, const short* __restrict__ Bt,
    const float* __restrict__ bias, const float* __restrict__ resid,
    void* __restrict__ OutP, int N, int K) {
  __shared__ short SMEM[32768];               // 64 KB: buf b at b*16384
  const int tid = threadIdx.x;
  const int wave = tid >> 6, lane = tid & 63;
  const int quad = lane >> 4, l15 = lane & 15;
  const int m0 = blockIdx.y * 128;
  const int n0 = blockIdx.x * 128;
  const int wm = (wave >> 1) * 64, wn = (wave & 1) * 64;

  f32x4 acc[4][4] = {};

  auto stage = [&](int b, int kk) {
    short* Asb = SMEM + b * 16384;
    short* Bsb = Asb + 8192;
#pragma unroll
    for (int i = 0; i < 4; ++i) {
      const int p = wave * 256 + i * 64 + lane;
      const int row = p >> 3;
      const int c = (p & 7) ^ (row & 7);
      GLDS16(A  + (size_t)(m0 + row) * K + (kk + c * 8),
             Asb + (size_t)(wave * 256 + i * 64) * 8);
      GLDS16(Bt + (size_t)(n0 + row) * K + (kk + c * 8),
             Bsb + (size_t)(wave * 256 + i * 64) * 8);
    }
  };
  auto compute = [&](int b) {
    const short* Asb = SMEM + b * 16384;
    const short* Bsb = Asb + 8192;
#pragma unroll
    for (int ks = 0; ks < 2; ++ks) {
      bf16x8 af[4], bfr[4];
#pragma unroll
      for (int t = 0; t < 4; ++t) {
        const int ra = wm + t * 16 + l15;
        const int ca = (ks * 4 + quad) ^ (ra & 7);
        af[t] = *(const bf16x8*)(Asb + ra * 64 + ca * 8);
        const int rb = wn + t * 16 + l15;
        const int cb = (ks * 4 + quad) ^ (rb & 7);
        bfr[t] = *(const bf16x8*)(Bsb + rb * 64 + cb * 8);
      }
#pragma unroll
      for (int mt = 0; mt < 4; ++mt)
#pragma unroll
        for (int nt = 0; nt < 4; ++nt)
          acc[mt][nt] = MFMA16(af[mt], bfr[nt], acc[mt][nt], 0, 0, 0);
    }
  };

  stage(0, 0);
  __syncthreads();
  int cur = 0;
  const int NT = K >> 6;
  for (int t = 0; t < NT - 1; ++t) {
    stage(cur ^ 1, (t + 1) * 64);
    compute(cur);
    __syncthreads();
    cur ^= 1;
  }
  compute(cur);

  __syncthreads();
  if constexpr (EPI == 1) {
#pragma unroll
    for (int nt = 0; nt < 4; ++nt) {
      const int col = wn + nt * 16 + l15;
      const float bv = bias[n0 + col];
#pragma unroll
      for (int mt = 0; mt < 4; ++mt)
#pragma unroll
        for (int reg = 0; reg < 4; ++reg) {
          const int row = wm + mt * 16 + quad * 4 + reg;
          float v = gelu_f(acc[mt][nt][reg] + bv);
          const int byte = (row << 8) | ((col << 1) ^ ((row & 7) << 4));
          *(short*)((char*)SMEM + byte) = f2bf(v);
        }
    }
    __syncthreads();
    short* out = (short*)OutP;
#pragma unroll
    for (int i = 0; i < 8; ++i) {
      const int off = i * 4096 + tid * 16;
      const int row = off >> 8;
      const bf16x8 val =
          *(const bf16x8*)((char*)SMEM + (off ^ ((row & 7) << 4)));
      *(bf16x8*)(out + (size_t)(m0 + row) * N + n0 + ((off & 255) >> 1)) = val;
    }
  } else {
    float* out = (float*)OutP;
#pragma unroll
    for (int hh = 0; hh < 2; ++hh) {
      if (hh) __syncthreads();
      if (wm == hh * 64) {
#pragma unroll
        for (int nt = 0; nt < 4; ++nt) {
          const int col = wn + nt * 16 + l15;
          const float bv = bias[n0 + col];
#pragma unroll
          for (int mt = 0; mt < 4; ++mt)
#pragma unroll
            for (int reg = 0; reg < 4; ++reg) {
              const int rloc = mt * 16 + quad * 4 + reg;
              const int byte = (rloc << 9) | ((col << 2) ^ ((rloc & 7) << 4));
              *(float*)((char*)SMEM + byte) = acc[mt][nt][reg] + bv;
            }
        }
      }
      __syncthreads();
#pragma unroll
      for (int i = 0; i < 8; ++i) {
        const int off = i * 4096 + tid * 16;
        const int rloc = off >> 9;
        f32x4 val = *(const f32x4*)((char*)SMEM + (off ^ ((rloc & 7) << 4)));
        const int colf = (off & 511) >> 2;
        const size_t dst = (size_t)(m0 + hh * 64 + rloc) * 256 + n0 + colf;
        const f32x4 r = *(const f32x4*)(resid + dst);
        val = val + r;
        *(f32x4*)(out + dst) = val;
      }
    }
  }
}

// ---------------------------------------------------------------------------
// Windowed attention. grid = 1568*2 blocks; 4 waves, 1 head/wave.
__global__ __launch_bounds__(256) void attn_k(
    const short* __restrict__ qkv, const float* __restrict__ rpb,
    short* __restrict__ aout) {
  __shared__ short Plds[4 * 64 * 80];
  const int tid = threadIdx.x;
  const int wave = tid >> 6, lane = tid & 63;
  const int quad = lane >> 4, l15 = lane & 15;
  const int win = blockIdx.x >> 1;
  const int h = ((blockIdx.x & 1) << 2) + wave;
  const int wi = win % 784;
  const int wd = wi / 196, wh = (wi / 14) % 14, ww = wi % 14;
  const short* base = qkv + (size_t)win * (64 * 768);

  bf16x8 qf[4], kf[4];
#pragma unroll
  for (int t = 0; t < 4; ++t) {
    const short* qp = base + (size_t)(t * 16 + l15) * 768 + h * 32 + quad * 8;
    qf[t] = *(const bf16x8*)qp;
    kf[t] = *(const bf16x8*)(qp + 256);
  }
  f32x4 S[4][4] = {};
#pragma unroll
  for (int mt = 0; mt < 4; ++mt)
#pragma unroll
    for (int nt = 0; nt < 4; ++nt)
      S[mt][nt] = MFMA16(qf[mt], kf[nt], S[mt][nt], 0, 0, 0);

  const bool bd = (wd == 3), bh = (wh == 13), bw = (ww == 13);
  const int yc = l15 >> 2, xc = l15 & 3;
  int labc[4];
#pragma unroll
  for (int nt = 0; nt < 4; ++nt) {
    const int rd = bd ? (nt < 2 ? 1 : 2) : 0;
    const int rh = bh ? (yc < 2 ? 1 : 2) : 0;
    const int rw = bw ? (xc < 2 ? 1 : 2) : 0;
    labc[nt] = rd * 9 + rh * 3 + rw;
  }
  const float scale = 0.17677669529663687f;   // 32^-0.5
#pragma unroll
  for (int mt = 0; mt < 4; ++mt) {
    const int rdr = bd ? (mt < 2 ? 1 : 2) : 0;
    const int rhr = bh ? (quad < 2 ? 1 : 2) : 0;
#pragma unroll
    for (int reg = 0; reg < 4; ++reg) {
      const int rwr = bw ? (reg < 2 ? 1 : 2) : 0;
      const int labr = rdr * 9 + rhr * 3 + rwr;
      float sc[4];
#pragma unroll
      for (int nt = 0; nt < 4; ++nt) {
        const int rpi = (mt - nt + 3) * 49 + (quad - yc + 3) * 7 + (reg - xc + 3);
        const float bias = rpb[rpi * 8 + h];
        const float mv = (labr == labc[nt]) ? 0.f : -100.f;
        sc[nt] = S[mt][nt][reg] * scale + bias + mv;
      }
      float mx = fmaxf(fmaxf(sc[0], sc[1]), fmaxf(sc[2], sc[3]));
      mx = fmaxf(mx, __shfl_xor(mx, 1));
      mx = fmaxf(mx, __shfl_xor(mx, 2));
      mx = fmaxf(mx, __shfl_xor(mx, 4));
      mx = fmaxf(mx, __shfl_xor(mx, 8));
      float p[4], sum = 0.f;
#pragma unroll
      for (int nt = 0; nt < 4; ++nt) { p[nt] = __expf(sc[nt] - mx); sum += p[nt]; }
      sum += __shfl_xor(sum, 1);
      sum += __shfl_xor(sum, 2);
      sum += __shfl_xor(sum, 4);
      sum += __shfl_xor(sum, 8);
      const float inv = 1.f / sum;
      const int r = mt * 16 + quad * 4 + reg;
#pragma unroll
      for (int nt = 0; nt < 4; ++nt)
        Plds[(wave * 64 + r) * 80 + nt * 16 + l15] = f2bf(p[nt] * inv);
    }
  }

  bf16x8 vf[2][2];
#pragma unroll
  for (int kt = 0; kt < 2; ++kt)
#pragma unroll
    for (int n2 = 0; n2 < 2; ++n2)
#pragma unroll
      for (int j = 0; j < 8; ++j)
        vf[kt][n2][j] =
            base[(size_t)(kt * 32 + quad * 8 + j) * 768 + 512 + h * 32 + n2 * 16 + l15];

  f32x4 O[4][2] = {};
#pragma unroll
  for (int mt = 0; mt < 4; ++mt) {
    const short* pr = &Plds[(wave * 64 + mt * 16 + l15) * 80 + quad * 8];
    const bf16x8 pa0 = *(const bf16x8*)pr;
    const bf16x8 pa1 = *(const bf16x8*)(pr + 32);
#pragma unroll
    for (int n2 = 0; n2 < 2; ++n2) {
      O[mt][n2] = MFMA16(pa0, vf[0][n2], O[mt][n2], 0, 0, 0);
      O[mt][n2] = MFMA16(pa1, vf[1][n2], O[mt][n2], 0, 0, 0);
    }
  }
#pragma unroll
  for (int mt = 0; mt < 4; ++mt)
#pragma unroll
    for (int n2 = 0; n2 < 2; ++n2)
#pragma unroll
      for (int reg = 0; reg < 4; ++reg) {
        const int tok = mt * 16 + quad * 4 + reg;
        aout[((size_t)win * 64 + tok) * 256 + h * 32 + n2 * 16 + l15] =
            f2bf(O[mt][n2][reg]);
      }
}

// ---------------------------------------------------------------------------
extern "C" void kernel_launch(void* const* d_in, const int* in_sizes, int n_in,
                              void* d_out, int out_size, void* d_ws,
                              size_t ws_size, hipStream_t stream) {
  const float* x      = (const float*)d_in[0];
  const float* n1g    = (const float*)d_in[1];
  const float* n1b    = (const float*)d_in[2];
  const float* qkv_w  = (const float*)d_in[3];
  const float* qkv_b  = (const float*)d_in[4];
  const float* proj_w = (const float*)d_in[5];
  const float* proj_b = (const float*)d_in[6];
  const float* rpb    = (const float*)d_in[7];
  const float* n2g    = (const float*)d_in[8];
  const float* n2b    = (const float*)d_in[9];
  const float* fc1_w  = (const float*)d_in[10];
  const float* fc1_b  = (const float*)d_in[11];
  const float* fc2_w  = (const float*)d_in[12];
  const float* fc2_b  = (const float*)d_in[13];

  char* ws = (char*)d_ws;
  short* wt_qkv  = (short*)(ws + 0);          //     393,216 B
  short* wt_proj = (short*)(ws + 393216);     //     131,072 B
  short* wt_fc1  = (short*)(ws + 524288);     //     524,288 B
  short* wt_fc2  = (short*)(ws + 1048576);    //     524,288 B
  short* bufS    = (short*)(ws + 1572864);    //  51,380,224 B (attn out)
  short* bufL    = (short*)(ws + 52953088);   // 205,520,896 B (qkv/h1)
  short* bufY    = (short*)(ws + 258473984);  //  51,380,224 B (yn)
  // total 309,854,208 B
  float* x1      = (float*)d_out;             // x1 lives in d_out (f32)

  transpose_all_k<<<3072, 256, 0, stream>>>(qkv_w, proj_w, fc1_w, fc2_w,
                                            wt_qkv, wt_proj, wt_fc1, wt_fc2);
  ln1qkv_k<<<1568, 512, 0, stream>>>(x, n1g, n1b, wt_qkv, qkv_b, bufL);
  attn_k<<<3136, 256, 0, stream>>>(bufL, rpb, bufS);
  projln2_k<<<1568, 256, 0, stream>>>(bufS, wt_proj, proj_b, x, n2g, n2b,
                                      x1, bufY);
  gemm_k<1><<<dim3(8, 784), 256, 0, stream>>>(bufY, wt_fc1, fc1_b, nullptr,
                                              bufL, 1024, 256);
  gemm_k<3><<<dim3(2, 784), 256, 0, stream>>>(bufL, wt_fc2, fc2_b, x1,
                                              x1, 256, 1024);
}

// Round 8
// 733.150 us; speedup vs baseline: 1.0512x; 1.0512x over previous
//
#include <hip/hip_runtime.h>
#include <math.h>

// ---------------------------------------------------------------------------
// SwinTransformerBlock3D  (B=2, D=16, H=56, W=56, C=256, heads=8, ws=4, ss=2)
// f32 in / f32 out. M = 100352 rows, 1568 windows. 6 launches:
//   transpose_all -> ln1qkv (fused LN1+roll+partition+qkv GEMM) -> attention
//   -> projln2 (proj GEMM + reverse+roll+resid + fused LN2) -> fc1 -> fc2
// Round 4 (WIN 734->706): LDS-bounce epilogue. Round 5: mlp_k failed.
// Round 6 (WIN 706->667): 2-phase dbuf gemm.
// Round 7: window fusion regressed 667->770: ln1qkv/projln2 read W fragments
//   per-lane strided (512B lane stride = 64 cache lines per load, ~3000 TA
//   transactions/wave) -> all pipes idle, 1.2 TB/s.
// Round 8: W fragment-PACKED layout (pack[(colTile*8+kt)*64+lane] = 16B frag)
//   emitted by transpose_all_k; ln1qkv/projln2 weight loads become
//   base + lane*16B (one coalesced 1KB txn). Numerics identical.
// GEMM (fc1/fc2): 2-phase dbuf, BK=64, glds16 + XOR swizzle, LDS-bounce epi.
// ---------------------------------------------------------------------------

using f32x4  = __attribute__((ext_vector_type(4))) float;
using bf16x8 = __attribute__((ext_vector_type(8))) short;

#define MFMA16 __builtin_amdgcn_mfma_f32_16x16x32_bf16

__device__ __forceinline__ short f2bf(float f) {
  unsigned u = __builtin_bit_cast(unsigned, f);
  u += 0x7fffu + ((u >> 16) & 1u);          // RNE
  return (short)(u >> 16);
}

__device__ __forceinline__ float gelu_f(float v) {
  const float u = 1.5957691216057308f * v * (1.f + 0.044715f * v * v);
  const float e = __expf(u);
  return v - v * __builtin_amdgcn_rcpf(e + 1.f);
}

#define GLDS16(g, l) __builtin_amdgcn_global_load_lds(                        \
    (__attribute__((address_space(1))) void*)(g),                             \
    (__attribute__((address_space(3))) void*)(l), 16, 0, 0)

// rolled-gather mapping (verified in ln1_part_k since round 0)
__device__ __forceinline__ size_t swin_src(int win, int tok) {
  const int b = win / 784, wi = win % 784;
  const int wd = wi / 196, wh = (wi / 14) % 14, ww = wi % 14;
  const int tz = tok >> 4, ty = (tok >> 2) & 3, tx = tok & 3;
  const int gd = (wd * 4 + tz + 2) & 15;
  int gh = wh * 4 + ty + 2; if (gh >= 56) gh -= 56;
  int gw = ww * 4 + tx + 2; if (gw >= 56) gw -= 56;
  return ((((size_t)b * 16 + gd) * 56 + gh) * 56 + gw) * 256;
}

// ---------------------------------------------------------------------------
// weight prep, one launch (2176 blocks):
//   fc1/fc2: [K][N] f32 -> [N][K] bf16 (for gemm_k staging)
//   qkv/proj: [K][N] f32 -> MFMA-fragment-packed bf16:
//     pack[((colTile*8 + ktile)*64 + lane)*8 + j] = W[ktile*32+(lane>>4)*8+j]
//                                                     [colTile*16+(lane&15)]
__global__ void transpose_all_k(const float* __restrict__ qkv_w,
                                const float* __restrict__ proj_w,
                                const float* __restrict__ fc1_w,
                                const float* __restrict__ fc2_w,
                                short* __restrict__ o_qkv,
                                short* __restrict__ o_proj,
                                short* __restrict__ o_fc1,
                                short* __restrict__ o_fc2) {
  const int bid = blockIdx.x;
  if (bid < 1024) {                       // fc1: K=256, N=1024
    const int idx = bid * 256 + threadIdx.x;
    const int k = idx >> 10, n = idx & 1023;
    o_fc1[(size_t)n * 256 + k] = f2bf(fc1_w[idx]);
  } else if (bid < 2048) {                // fc2: K=1024, N=256
    const int idx = (bid - 1024) * 256 + threadIdx.x;
    const int k = idx >> 8, n = idx & 255;
    o_fc2[(size_t)n * 1024 + k] = f2bf(fc2_w[idx]);
  } else if (bid < 2144) {                // qkv fragment-pack (N=768, K=256)
    const int idx = (bid - 2048) * 256 + threadIdx.x;   // 0..24575
    const int lane = idx & 63, tile = idx >> 6;         // tile 0..383
    const int kt = tile & 7, ct = tile >> 3;            // ct 0..47
    const int n = ct * 16 + (lane & 15);
    const int kb = kt * 32 + (lane >> 4) * 8;
    bf16x8 o;
#pragma unroll
    for (int j = 0; j < 8; ++j)
      o[j] = f2bf(qkv_w[(size_t)(kb + j) * 768 + n]);
    *(bf16x8*)(o_qkv + (size_t)idx * 8) = o;
  } else {                                // proj fragment-pack (N=256, K=256)
    const int idx = (bid - 2144) * 256 + threadIdx.x;   // 0..8191
    const int lane = idx & 63, tile = idx >> 6;         // tile 0..127
    const int kt = tile & 7, ct = tile >> 3;            // ct 0..15
    const int n = ct * 16 + (lane & 15);
    const int kb = kt * 32 + (lane >> 4) * 8;
    bf16x8 o;
#pragma unroll
    for (int j = 0; j < 8; ++j)
      o[j] = f2bf(proj_w[(size_t)(kb + j) * 256 + n]);
    *(bf16x8*)(o_proj + (size_t)idx * 8) = o;
  }
}

// ---------------------------------------------------------------------------
// Fused LN1 + roll + window partition + qkv GEMM.  1 block = 1 window.
// 512 threads = 8 waves; wave h computes head h's 64x96 qkv slice.
// LDS 32KB: Xn [64][256] bf16 (chunk ^ row&7 swizzle), reused as bounce Cs.
// Weight loads: fragment-packed, base + lane*16B (coalesced).
__global__ __launch_bounds__(512) void ln1qkv_k(
    const float* __restrict__ x, const float* __restrict__ g,
    const float* __restrict__ bta, const short* __restrict__ Wq,  // packed
    const float* __restrict__ qb, short* __restrict__ qkv) {
  __shared__ __align__(16) char SM[32768];
  const int tid = threadIdx.x;
  const int win = blockIdx.x;

  // ---- phase A: LN1 (8 lanes per token)
  {
    const int tk = tid >> 3, lane3 = tid & 7;
    const size_t src = swin_src(win, tk);
    f32x4 xr[8];
#pragma unroll
    for (int i = 0; i < 8; ++i)
      xr[i] = *(const f32x4*)(x + src + lane3 * 32 + i * 4);
    float s = 0.f;
#pragma unroll
    for (int i = 0; i < 8; ++i) s += xr[i][0] + xr[i][1] + xr[i][2] + xr[i][3];
    s += __shfl_xor(s, 1); s += __shfl_xor(s, 2); s += __shfl_xor(s, 4);
    const float mean = s * (1.f / 256.f);
    float q = 0.f;
#pragma unroll
    for (int i = 0; i < 8; ++i)
#pragma unroll
      for (int j = 0; j < 4; ++j) {
        const float d = xr[i][j] - mean; q += d * d;
      }
    q += __shfl_xor(q, 1); q += __shfl_xor(q, 2); q += __shfl_xor(q, 4);
    const float rstd = rsqrtf(q * (1.f / 256.f) + 1e-5f);
#pragma unroll
    for (int cc = 0; cc < 4; ++cc) {
      const float4 g0 = *(const float4*)(g + lane3 * 32 + cc * 8);
      const float4 g1 = *(const float4*)(g + lane3 * 32 + cc * 8 + 4);
      const float4 b0 = *(const float4*)(bta + lane3 * 32 + cc * 8);
      const float4 b1 = *(const float4*)(bta + lane3 * 32 + cc * 8 + 4);
      const f32x4 va = xr[cc * 2], vb = xr[cc * 2 + 1];
      bf16x8 o;
      o[0] = f2bf((va[0] - mean) * rstd * g0.x + b0.x);
      o[1] = f2bf((va[1] - mean) * rstd * g0.y + b0.y);
      o[2] = f2bf((va[2] - mean) * rstd * g0.z + b0.z);
      o[3] = f2bf((va[3] - mean) * rstd * g0.w + b0.w);
      o[4] = f2bf((vb[0] - mean) * rstd * g1.x + b1.x);
      o[5] = f2bf((vb[1] - mean) * rstd * g1.y + b1.y);
      o[6] = f2bf((vb[2] - mean) * rstd * g1.z + b1.z);
      o[7] = f2bf((vb[3] - mean) * rstd * g1.w + b1.w);
      const int byte = tk * 512 + (((lane3 * 4 + cc) ^ (tk & 7)) << 4);
      *(bf16x8*)(SM + byte) = o;
    }
  }
  __syncthreads();

  // ---- phase B: qkv MFMA (wave = head); W frags packed & coalesced
  const int wave = tid >> 6, lane = tid & 63;
  const int quad = lane >> 4, l15 = lane & 15;
  const int h = wave;
  f32x4 acc[3][2][4] = {};
#pragma unroll
  for (int kk = 0; kk < 8; ++kk) {
    bf16x8 af[4];
#pragma unroll
    for (int mt = 0; mt < 4; ++mt) {
      const int t = mt * 16 + l15;
      const int byte = t * 512 + (((kk * 4 + quad) ^ (t & 7)) << 4);
      af[mt] = *(const bf16x8*)(SM + byte);
    }
#pragma unroll
    for (int gq = 0; gq < 3; ++gq)
#pragma unroll
      for (int ct = 0; ct < 2; ++ct) {
        const int colTile = gq * 16 + h * 2 + ct;
        const bf16x8 bfr =
            *(const bf16x8*)(Wq + (size_t)((colTile * 8 + kk) * 64 + lane) * 8);
#pragma unroll
        for (int mt = 0; mt < 4; ++mt)
          acc[gq][ct][mt] = MFMA16(af[mt], bfr, acc[gq][ct][mt], 0, 0, 0);
      }
  }

  // ---- phase C: bounce each 256-col plane through LDS, coalesced write
  short* const outp = qkv + (size_t)win * 64 * 768;
#pragma unroll
  for (int gq = 0; gq < 3; ++gq) {
    __syncthreads();                      // prior readers of SM done
#pragma unroll
    for (int ct = 0; ct < 2; ++ct)
#pragma unroll
      for (int mt = 0; mt < 4; ++mt)
#pragma unroll
        for (int reg = 0; reg < 4; ++reg) {
          const int t = mt * 16 + quad * 4 + reg;
          const int col = h * 32 + ct * 16 + l15;
          const float v = acc[gq][ct][mt][reg] + qb[gq * 256 + col];
          const int cb = col * 2;
          const int byte = t * 512 + (((cb >> 4) ^ (t & 7)) << 4) + (cb & 15);
          *(short*)(SM + byte) = f2bf(v);
        }
    __syncthreads();
#pragma unroll
    for (int i = 0; i < 4; ++i) {
      const int off = i * 8192 + tid * 16;
      const int row = off >> 9, cb = off & 511;
      const bf16x8 val = *(const bf16x8*)(SM + (off ^ ((row & 7) << 4)));
      *(bf16x8*)(outp + (size_t)row * 768 + gq * 256 + (cb >> 1)) = val;
    }
  }
}

// ---------------------------------------------------------------------------
// Fused proj GEMM + window-reverse + roll + residual + LN2. 1 block = 64 rows.
// 256 threads = 4 waves; wave w owns out cols w*64..w*64+64 (all 64 tokens).
// LDS 64KB: As [64][256] bf16 32KB (staged), reused as Cs f32 [64][256] 64KB.
// Weight loads: fragment-packed, base + lane*16B (coalesced).
__global__ __launch_bounds__(256) void projln2_k(
    const short* __restrict__ ao, const short* __restrict__ Wp,  // packed
    const float* __restrict__ pb, const float* __restrict__ xres,
    const float* __restrict__ g2, const float* __restrict__ b2,
    float* __restrict__ x1, short* __restrict__ yn) {
  __shared__ __align__(16) char SM[65536];
  const int tid = threadIdx.x;
  const int wave = tid >> 6, lane = tid & 63;
  const int quad = lane >> 4, l15 = lane & 15;
  const int m0 = blockIdx.x * 64;

  // stage As [64][256] bf16 with chunk^row&7 swizzle (32 chunks/row)
#pragma unroll
  for (int i = 0; i < 8; ++i) {
    const int p = i * 256 + tid;
    const int row = p >> 5;
    const int c = (p & 31) ^ (row & 7);
    GLDS16(ao + (size_t)(m0 + row) * 256 + c * 8, SM + p * 16);
  }
  __syncthreads();

  f32x4 pacc[4][4] = {};
#pragma unroll
  for (int kk = 0; kk < 8; ++kk) {
    bf16x8 af[4];
#pragma unroll
    for (int mt = 0; mt < 4; ++mt) {
      const int t = mt * 16 + l15;
      const int byte = t * 512 + (((kk * 4 + quad) ^ (t & 7)) << 4);
      af[mt] = *(const bf16x8*)(SM + byte);
    }
#pragma unroll
    for (int nt = 0; nt < 4; ++nt) {
      const int colTile = wave * 4 + nt;
      const bf16x8 bfr =
          *(const bf16x8*)(Wp + (size_t)((colTile * 8 + kk) * 64 + lane) * 8);
#pragma unroll
      for (int mt = 0; mt < 4; ++mt)
        pacc[mt][nt] = MFMA16(af[mt], bfr, pacc[mt][nt], 0, 0, 0);
    }
  }

  // bounce to Cs f32 [64][256] (64 chunks/row, chunk^row&7)
  __syncthreads();
#pragma unroll
  for (int nt = 0; nt < 4; ++nt) {
    const int col = wave * 64 + nt * 16 + l15;
    const float bv = pb[col];
#pragma unroll
    for (int mt = 0; mt < 4; ++mt)
#pragma unroll
      for (int reg = 0; reg < 4; ++reg) {
        const int t = mt * 16 + quad * 4 + reg;
        const int byte =
            t * 1024 + ((((col >> 2)) ^ (t & 7)) << 4) + (col & 3) * 4;
        *(float*)(SM + byte) = pacc[mt][nt][reg] + bv;
      }
  }
  __syncthreads();

  // final: 4 lanes per token; +resid (rolled) -> x1, LN2 -> yn
  const int tok = tid >> 2, lane2 = tid & 3;
  const size_t src = swin_src(blockIdx.x, tok);
  f32x4 x1v[16];
  float s = 0.f;
#pragma unroll
  for (int cc = 0; cc < 16; ++cc) {
    const int ch = lane2 * 16 + cc;
    f32x4 v = *(const f32x4*)(SM + tok * 1024 + ((ch ^ (tok & 7)) << 4));
    const f32x4 r = *(const f32x4*)(xres + src + lane2 * 64 + cc * 4);
    v = v + r;
    x1v[cc] = v;
    s += v[0] + v[1] + v[2] + v[3];
  }
  s += __shfl_xor(s, 1); s += __shfl_xor(s, 2);
  const float mean = s * (1.f / 256.f);
  float q = 0.f;
#pragma unroll
  for (int cc = 0; cc < 16; ++cc)
#pragma unroll
    for (int j = 0; j < 4; ++j) {
      const float d = x1v[cc][j] - mean; q += d * d;
    }
  q += __shfl_xor(q, 1); q += __shfl_xor(q, 2);
  const float rstd = rsqrtf(q * (1.f / 256.f) + 1e-5f);
#pragma unroll
  for (int cc = 0; cc < 16; ++cc)
    *(f32x4*)(x1 + src + lane2 * 64 + cc * 4) = x1v[cc];
#pragma unroll
  for (int u = 0; u < 8; ++u) {
    const float4 gA = *(const float4*)(g2 + lane2 * 64 + u * 8);
    const float4 gB = *(const float4*)(g2 + lane2 * 64 + u * 8 + 4);
    const float4 bA = *(const float4*)(b2 + lane2 * 64 + u * 8);
    const float4 bB = *(const float4*)(b2 + lane2 * 64 + u * 8 + 4);
    const f32x4 va = x1v[u * 2], vb = x1v[u * 2 + 1];
    bf16x8 o;
    o[0] = f2bf((va[0] - mean) * rstd * gA.x + bA.x);
    o[1] = f2bf((va[1] - mean) * rstd * gA.y + bA.y);
    o[2] = f2bf((va[2] - mean) * rstd * gA.z + bA.z);
    o[3] = f2bf((va[3] - mean) * rstd * gA.w + bA.w);
    o[4] = f2bf((vb[0] - mean) * rstd * gB.x + bB.x);
    o[5] = f2bf((vb[1] - mean) * rstd * gB.y + bB.y);
    o[6] = f2bf((vb[2] - mean) * rstd * gB.z + bB.z);
    o[7] = f2bf((vb[3] - mean) * rstd * gB.w + bB.w);
    *(bf16x8*)(yn + src + lane2 * 64 + u * 8) = o;
  }
}

// ---------------------------------------------------------------------------
// bf16 MFMA GEMM (fc1/fc2): 128x128 tile, BK=64, 2-phase dbuf, LDS-bounce epi.
// EPI: 1=bf16 GELU store, 3=f32 +resid(f32) -> d_out (linear rows)
template <int EPI>
__global__ __launch_bounds__(256) void gemm_k(
    const short* __restrict__ A, const short* __restrict__ Bt,
    const float* __restrict__ bias, const float* __restrict__ resid,
    void* __restrict__ OutP, int N, int K) {
  __shared__ short SMEM[32768];               // 64 KB: buf b at b*16384
  const int tid = threadIdx.x;
  const int wave = tid >> 6, lane = tid & 63;
  const int quad = lane >> 4, l15 = lane & 15;
  const int m0 = blockIdx.y * 128;
  const int n0 = blockIdx.x * 128;
  const int wm = (wave >> 1) * 64, wn = (wave & 1) * 64;

  f32x4 acc[4][4] = {};

  auto stage = [&](int b, int kk) {
    short* Asb = SMEM + b * 16384;
    short* Bsb = Asb + 8192;
#pragma unroll
    for (int i = 0; i < 4; ++i) {
      const int p = wave * 256 + i * 64 + lane;
      const int row = p >> 3;
      const int c = (p & 7) ^ (row & 7);
      GLDS16(A  + (size_t)(m0 + row) * K + (kk + c * 8),
             Asb + (size_t)(wave * 256 + i * 64) * 8);
      GLDS16(Bt + (size_t)(n0 + row) * K + (kk + c * 8),
             Bsb + (size_t)(wave * 256 + i * 64) * 8);
    }
  };
  auto compute = [&](int b) {
    const short* Asb = SMEM + b * 16384;
    const short* Bsb = Asb + 8192;
#pragma unroll
    for (int ks = 0; ks < 2; ++ks) {
      bf16x8 af[4], bfr[4];
#pragma unroll
      for (int t = 0; t < 4; ++t) {
        const int ra = wm + t * 16 + l15;
        const int ca = (ks * 4 + quad) ^ (ra & 7);
        af[t] = *(const bf16x8*)(Asb + ra * 64 + ca * 8);
        const int rb = wn + t * 16 + l15;
        const int cb = (ks * 4 + quad) ^ (rb & 7);
        bfr[t] = *(const bf16x8*)(Bsb + rb * 64 + cb * 8);
      }
#pragma unroll
      for (int mt = 0; mt < 4; ++mt)
#pragma unroll
        for (int nt = 0; nt < 4; ++nt)
          acc[mt][nt] = MFMA16(af[mt], bfr[nt], acc[mt][nt], 0, 0, 0);
    }
  };

  stage(0, 0);
  __syncthreads();
  int cur = 0;
  const int NT = K >> 6;
  for (int t = 0; t < NT - 1; ++t) {
    stage(cur ^ 1, (t + 1) * 64);
    compute(cur);
    __syncthreads();
    cur ^= 1;
  }
  compute(cur);

  __syncthreads();
  if constexpr (EPI == 1) {
#pragma unroll
    for (int nt = 0; nt < 4; ++nt) {
      const int col = wn + nt * 16 + l15;
      const float bv = bias[n0 + col];
#pragma unroll
      for (int mt = 0; mt < 4; ++mt)
#pragma unroll
        for (int reg = 0; reg < 4; ++reg) {
          const int row = wm + mt * 16 + quad * 4 + reg;
          float v = gelu_f(acc[mt][nt][reg] + bv);
          const int byte = (row << 8) | ((col << 1) ^ ((row & 7) << 4));
          *(short*)((char*)SMEM + byte) = f2bf(v);
        }
    }
    __syncthreads();
    short* out = (short*)OutP;
#pragma unroll
    for (int i = 0; i < 8; ++i) {
      const int off = i * 4096 + tid * 16;
      const int row = off >> 8;
      const bf16x8 val =
          *(const bf16x8*)((char*)SMEM + (off ^ ((row & 7) << 4)));
      *(bf16x8*)(out + (size_t)(m0 + row) * N + n0 + ((off & 255) >> 1)) = val;
    }
  } else {
    float* out = (float*)OutP;
#pragma unroll
    for (int hh = 0; hh < 2; ++hh) {
      if (hh) __syncthreads();
      if (wm == hh * 64) {
#pragma unroll
        for (int nt = 0; nt < 4; ++nt) {
          const int col = wn + nt * 16 + l15;
          const float bv = bias[n0 + col];
#pragma unroll
          for (int mt = 0; mt < 4; ++mt)
#pragma unroll
            for (int reg = 0; reg < 4; ++reg) {
              const int rloc = mt * 16 + quad * 4 + reg;
              const int byte = (rloc << 9) | ((col << 2) ^ ((rloc & 7) << 4));
              *(float*)((char*)SMEM + byte) = acc[mt][nt][reg] + bv;
            }
        }
      }
      __syncthreads();
#pragma unroll
      for (int i = 0; i < 8; ++i) {
        const int off = i * 4096 + tid * 16;
        const int rloc = off >> 9;
        f32x4 val = *(const f32x4*)((char*)SMEM + (off ^ ((rloc & 7) << 4)));
        const int colf = (off & 511) >> 2;
        const size_t dst = (size_t)(m0 + hh * 64 + rloc) * 256 + n0 + colf;
        const f32x4 r = *(const f32x4*)(resid + dst);
        val = val + r;
        *(f32x4*)(out + dst) = val;
      }
    }
  }
}

// ---------------------------------------------------------------------------
// Windowed attention. grid = 1568*2 blocks; 4 waves, 1 head/wave.
__global__ __launch_bounds__(256) void attn_k(
    const short* __restrict__ qkv, const float* __restrict__ rpb,
    short* __restrict__ aout) {
  __shared__ short Plds[4 * 64 * 80];
  const int tid = threadIdx.x;
  const int wave = tid >> 6, lane = tid & 63;
  const int quad = lane >> 4, l15 = lane & 15;
  const int win = blockIdx.x >> 1;
  const int h = ((blockIdx.x & 1) << 2) + wave;
  const int wi = win % 784;
  const int wd = wi / 196, wh = (wi / 14) % 14, ww = wi % 14;
  const short* base = qkv + (size_t)win * (64 * 768);

  bf16x8 qf[4], kf[4];
#pragma unroll
  for (int t = 0; t < 4; ++t) {
    const short* qp = base + (size_t)(t * 16 + l15) * 768 + h * 32 + quad * 8;
    qf[t] = *(const bf16x8*)qp;
    kf[t] = *(const bf16x8*)(qp + 256);
  }
  f32x4 S[4][4] = {};
#pragma unroll
  for (int mt = 0; mt < 4; ++mt)
#pragma unroll
    for (int nt = 0; nt < 4; ++nt)
      S[mt][nt] = MFMA16(qf[mt], kf[nt], S[mt][nt], 0, 0, 0);

  const bool bd = (wd == 3), bh = (wh == 13), bw = (ww == 13);
  const int yc = l15 >> 2, xc = l15 & 3;
  int labc[4];
#pragma unroll
  for (int nt = 0; nt < 4; ++nt) {
    const int rd = bd ? (nt < 2 ? 1 : 2) : 0;
    const int rh = bh ? (yc < 2 ? 1 : 2) : 0;
    const int rw = bw ? (xc < 2 ? 1 : 2) : 0;
    labc[nt] = rd * 9 + rh * 3 + rw;
  }
  const float scale = 0.17677669529663687f;   // 32^-0.5
#pragma unroll
  for (int mt = 0; mt < 4; ++mt) {
    const int rdr = bd ? (mt < 2 ? 1 : 2) : 0;
    const int rhr = bh ? (quad < 2 ? 1 : 2) : 0;
#pragma unroll
    for (int reg = 0; reg < 4; ++reg) {
      const int rwr = bw ? (reg < 2 ? 1 : 2) : 0;
      const int labr = rdr * 9 + rhr * 3 + rwr;
      float sc[4];
#pragma unroll
      for (int nt = 0; nt < 4; ++nt) {
        const int rpi = (mt - nt + 3) * 49 + (quad - yc + 3) * 7 + (reg - xc + 3);
        const float bias = rpb[rpi * 8 + h];
        const float mv = (labr == labc[nt]) ? 0.f : -100.f;
        sc[nt] = S[mt][nt][reg] * scale + bias + mv;
      }
      float mx = fmaxf(fmaxf(sc[0], sc[1]), fmaxf(sc[2], sc[3]));
      mx = fmaxf(mx, __shfl_xor(mx, 1));
      mx = fmaxf(mx, __shfl_xor(mx, 2));
      mx = fmaxf(mx, __shfl_xor(mx, 4));
      mx = fmaxf(mx, __shfl_xor(mx, 8));
      float p[4], sum = 0.f;
#pragma unroll
      for (int nt = 0; nt < 4; ++nt) { p[nt] = __expf(sc[nt] - mx); sum += p[nt]; }
      sum += __shfl_xor(sum, 1);
      sum += __shfl_xor(sum, 2);
      sum += __shfl_xor(sum, 4);
      sum += __shfl_xor(sum, 8);
      const float inv = 1.f / sum;
      const int r = mt * 16 + quad * 4 + reg;
#pragma unroll
      for (int nt = 0; nt < 4; ++nt)
        Plds[(wave * 64 + r) * 80 + nt * 16 + l15] = f2bf(p[nt] * inv);
    }
  }

  bf16x8 vf[2][2];
#pragma unroll
  for (int kt = 0; kt < 2; ++kt)
#pragma unroll
    for (int n2 = 0; n2 < 2; ++n2)
#pragma unroll
      for (int j = 0; j < 8; ++j)
        vf[kt][n2][j] =
            base[(size_t)(kt * 32 + quad * 8 + j) * 768 + 512 + h * 32 + n2 * 16 + l15];

  f32x4 O[4][2] = {};
#pragma unroll
  for (int mt = 0; mt < 4; ++mt) {
    const short* pr = &Plds[(wave * 64 + mt * 16 + l15) * 80 + quad * 8];
    const bf16x8 pa0 = *(const bf16x8*)pr;
    const bf16x8 pa1 = *(const bf16x8*)(pr + 32);
#pragma unroll
    for (int n2 = 0; n2 < 2; ++n2) {
      O[mt][n2] = MFMA16(pa0, vf[0][n2], O[mt][n2], 0, 0, 0);
      O[mt][n2] = MFMA16(pa1, vf[1][n2], O[mt][n2], 0, 0, 0);
    }
  }
#pragma unroll
  for (int mt = 0; mt < 4; ++mt)
#pragma unroll
    for (int n2 = 0; n2 < 2; ++n2)
#pragma unroll
      for (int reg = 0; reg < 4; ++reg) {
        const int tok = mt * 16 + quad * 4 + reg;
        aout[((size_t)win * 64 + tok) * 256 + h * 32 + n2 * 16 + l15] =
            f2bf(O[mt][n2][reg]);
      }
}

// ---------------------------------------------------------------------------
extern "C" void kernel_launch(void* const* d_in, const int* in_sizes, int n_in,
                              void* d_out, int out_size, void* d_ws,
                              size_t ws_size, hipStream_t stream) {
  const float* x      = (const float*)d_in[0];
  const float* n1g    = (const float*)d_in[1];
  const float* n1b    = (const float*)d_in[2];
  const float* qkv_w  = (const float*)d_in[3];
  const float* qkv_b  = (const float*)d_in[4];
  const float* proj_w = (const float*)d_in[5];
  const float* proj_b = (const float*)d_in[6];
  const float* rpb    = (const float*)d_in[7];
  const float* n2g    = (const float*)d_in[8];
  const float* n2b    = (const float*)d_in[9];
  const float* fc1_w  = (const float*)d_in[10];
  const float* fc1_b  = (const float*)d_in[11];
  const float* fc2_w  = (const float*)d_in[12];
  const float* fc2_b  = (const float*)d_in[13];

  char* ws = (char*)d_ws;
  short* wt_qkv  = (short*)(ws + 0);          //     393,216 B (frag-packed)
  short* wt_proj = (short*)(ws + 393216);     //     131,072 B (frag-packed)
  short* wt_fc1  = (short*)(ws + 524288);     //     524,288 B
  short* wt_fc2  = (short*)(ws + 1048576);    //     524,288 B
  short* bufS    = (short*)(ws + 1572864);    //  51,380,224 B (attn out)
  short* bufL    = (short*)(ws + 52953088);   // 205,520,896 B (qkv/h1)
  short* bufY    = (short*)(ws + 258473984);  //  51,380,224 B (yn)
  // total 309,854,208 B
  float* x1      = (float*)d_out;             // x1 lives in d_out (f32)

  transpose_all_k<<<2176, 256, 0, stream>>>(qkv_w, proj_w, fc1_w, fc2_w,
                                            wt_qkv, wt_proj, wt_fc1, wt_fc2);
  ln1qkv_k<<<1568, 512, 0, stream>>>(x, n1g, n1b, wt_qkv, qkv_b, bufL);
  attn_k<<<3136, 256, 0, stream>>>(bufL, rpb, bufS);
  projln2_k<<<1568, 256, 0, stream>>>(bufS, wt_proj, proj_b, x, n2g, n2b,
                                      x1, bufY);
  gemm_k<1><<<dim3(8, 784), 256, 0, stream>>>(bufY, wt_fc1, fc1_b, nullptr,
                                              bufL, 1024, 256);
  gemm_k<3><<<dim3(2, 784), 256, 0, stream>>>(bufL, wt_fc2, fc2_b, x1,
                                              x1, 256, 1024);
}

// Round 9
// 659.661 us; speedup vs baseline: 1.1683x; 1.1114x over previous
//
#include <hip/hip_runtime.h>
#include <math.h>

// ---------------------------------------------------------------------------
// SwinTransformerBlock3D  (B=2, D=16, H=56, W=56, C=256, heads=8, ws=4, ss=2)
// f32 in / f32 out. M = 100352 rows, 1568 windows. 8 launches (round-6 base):
//   transpose_all -> ln1+roll+partition -> qkv GEMM -> attention
//   -> proj GEMM(+reverse+roll+resid -> d_out f32) -> ln2
//   -> fc1 GEMM(+GELU) -> fc2 GEMM(+resid, in-place d_out)
// History: R4 (WIN 734->706) LDS-bounce epilogue. R5 mlp fusion failed.
//   R6 (WIN 706->667) 2-phase dbuf K-loop. R7/R8 window fusion failed
//   (152us ln1qkv vs 96 split; serial phases + <1 block/CU). REVERTED to R6.
// Round 9:
//   (a) XCD swizzle on fc1 ONLY, retested under dbuf (R6 fc1 FETCH=201MB =
//       4x A-size; R2's negative test was on the latency-bound single-buffer
//       kernel). Template flag isolates it.
//   (b) qkv output in head-major layout [win][h][q/k/v][64][32] — free change
//       in gemm<0>'s LDS-bounce store address; makes attn Q/K fragment loads
//       fully coalesced 1KB wave transactions (were 64x16B scatters).
// GEMM: BK=64, glds16 + XOR swizzle, 2-phase dbuf, LDS-bounce epilogue.
// ---------------------------------------------------------------------------

using f32x4  = __attribute__((ext_vector_type(4))) float;
using bf16x8 = __attribute__((ext_vector_type(8))) short;

#define MFMA16 __builtin_amdgcn_mfma_f32_16x16x32_bf16

__device__ __forceinline__ short f2bf(float f) {
  unsigned u = __builtin_bit_cast(unsigned, f);
  u += 0x7fffu + ((u >> 16) & 1u);          // RNE
  return (short)(u >> 16);
}

__device__ __forceinline__ float gelu_f(float v) {
  const float u = 1.5957691216057308f * v * (1.f + 0.044715f * v * v);
  const float e = __expf(u);
  return v - v * __builtin_amdgcn_rcpf(e + 1.f);
}

#define GLDS16(g, l) __builtin_amdgcn_global_load_lds(                        \
    (__attribute__((address_space(1))) void*)(g),                             \
    (__attribute__((address_space(3))) void*)(l), 16, 0, 0)

// ---------------------------------------------------------------------------
// all four weight transposes in one launch: [K][N] f32 -> [N][K] bf16
__global__ void transpose_all_k(const float* __restrict__ qkv_w,
                                const float* __restrict__ proj_w,
                                const float* __restrict__ fc1_w,
                                const float* __restrict__ fc2_w,
                                short* __restrict__ o_qkv,
                                short* __restrict__ o_proj,
                                short* __restrict__ o_fc1,
                                short* __restrict__ o_fc2) {
  int bid = blockIdx.x;
  const float* in; short* out; int K, N;
  if (bid < 768)       { in = qkv_w;  out = o_qkv;  K = 256;  N = 768; }
  else if (bid < 1024) { in = proj_w; out = o_proj; K = 256;  N = 256;  bid -= 768; }
  else if (bid < 2048) { in = fc1_w;  out = o_fc1;  K = 256;  N = 1024; bid -= 1024; }
  else                 { in = fc2_w;  out = o_fc2;  K = 1024; N = 256;  bid -= 2048; }
  const int idx = bid * 256 + threadIdx.x;
  const int k = idx / N, n = idx % N;
  out[(size_t)n * K + k] = f2bf(in[idx]);
}

// ---------------------------------------------------------------------------
// LN1 + roll(-2) + window partition.  One wave per output row.
__global__ __launch_bounds__(256) void ln1_part_k(
    const float* __restrict__ x, const float* __restrict__ g,
    const float* __restrict__ bta, short* __restrict__ xw) {
  const int wave = threadIdx.x >> 6, lane = threadIdx.x & 63;
  const int row = blockIdx.x * 4 + wave;
  const int win = row >> 6, tok = row & 63;
  const int b = win / 784, wi = win % 784;
  const int wd = wi / 196, wh = (wi / 14) % 14, ww = wi % 14;
  const int tz = tok >> 4, ty = (tok >> 2) & 3, tx = tok & 3;
  const int gd = (wd * 4 + tz + 2) & 15;
  int gh = wh * 4 + ty + 2; if (gh >= 56) gh -= 56;
  int gw = ww * 4 + tx + 2; if (gw >= 56) gw -= 56;
  const size_t src = ((((size_t)b * 16 + gd) * 56 + gh) * 56 + gw) * 256;
  const float4 v = ((const float4*)(x + src))[lane];
  float s = v.x + v.y + v.z + v.w;
#pragma unroll
  for (int m = 1; m < 64; m <<= 1) s += __shfl_xor(s, m);
  const float mean = s * (1.f / 256.f);
  const float dx = v.x - mean, dy = v.y - mean, dz = v.z - mean, dw = v.w - mean;
  float q = dx * dx + dy * dy + dz * dz + dw * dw;
#pragma unroll
  for (int m = 1; m < 64; m <<= 1) q += __shfl_xor(q, m);
  const float rstd = rsqrtf(q * (1.f / 256.f) + 1e-5f);
  const float4 gg = ((const float4*)g)[lane];
  const float4 bb = ((const float4*)bta)[lane];
  short4 o;
  o.x = f2bf(dx * rstd * gg.x + bb.x);
  o.y = f2bf(dy * rstd * gg.y + bb.y);
  o.z = f2bf(dz * rstd * gg.z + bb.z);
  o.w = f2bf(dw * rstd * gg.w + bb.w);
  *(short4*)(xw + (size_t)row * 256 + lane * 4) = o;
}

// LN2: reads f32 x1 (== d_out), writes bf16 yn
__global__ __launch_bounds__(256) void ln2_k(
    const float* __restrict__ x1, const float* __restrict__ g,
    const float* __restrict__ bta, short* __restrict__ yn) {
  const int wave = threadIdx.x >> 6, lane = threadIdx.x & 63;
  const int row = blockIdx.x * 4 + wave;
  const float4 v = ((const float4*)(x1 + (size_t)row * 256))[lane];
  float s = v.x + v.y + v.z + v.w;
#pragma unroll
  for (int m = 1; m < 64; m <<= 1) s += __shfl_xor(s, m);
  const float mean = s * (1.f / 256.f);
  const float dx = v.x - mean, dy = v.y - mean, dz = v.z - mean, dw = v.w - mean;
  float q = dx * dx + dy * dy + dz * dz + dw * dw;
#pragma unroll
  for (int m = 1; m < 64; m <<= 1) q += __shfl_xor(q, m);
  const float rstd = rsqrtf(q * (1.f / 256.f) + 1e-5f);
  const float4 gg = ((const float4*)g)[lane];
  const float4 bb = ((const float4*)bta)[lane];
  short4 o;
  o.x = f2bf(dx * rstd * gg.x + bb.x);
  o.y = f2bf(dy * rstd * gg.y + bb.y);
  o.z = f2bf(dz * rstd * gg.z + bb.z);
  o.w = f2bf(dw * rstd * gg.w + bb.w);
  *(short4*)(yn + (size_t)row * 256 + lane * 4) = o;
}

// ---------------------------------------------------------------------------
// bf16 MFMA GEMM: C[M,N] = A[M,K] * Bt[N,K]^T + bias. 128x128 tile, BK=64,
// glds16 + XOR swizzle, 2-phase dbuf K-loop, LDS-bounce epilogue.
// EPI: 0=bf16 store in HEAD-MAJOR qkv layout [win][h][gq][64][32]
//      1=bf16 GELU store (linear [M][N])
//      2=f32 swin-reverse+roll+resid(x f32) scatter -> d_out
//      3=f32 +resid(f32) -> d_out (linear rows)
// XSWZ: bijective XCD swizzle (nwg % 8 == 0 required); fc1 only this round.
template <int EPI, int XSWZ>
__global__ __launch_bounds__(256) void gemm_k(
    const short* __restrict__ A, const short* __restrict__ Bt,
    const float* __restrict__ bias, const float* __restrict__ resid,
    void* __restrict__ OutP, int N, int K) {
  __shared__ short SMEM[32768];               // 64 KB: buf b at b*16384
  const int tid = threadIdx.x;
  const int wave = tid >> 6, lane = tid & 63;
  const int quad = lane >> 4, l15 = lane & 15;
  int m0, n0;
  if constexpr (XSWZ) {
    const int gx = gridDim.x;
    int lin = blockIdx.y * gx + blockIdx.x;   // hw dispatch order (x fastest)
    const int q8 = (gx * gridDim.y) >> 3;
    lin = (lin & 7) * q8 + (lin >> 3);        // XCD -> contiguous tile chunk
    m0 = (lin / gx) * 128;
    n0 = (lin % gx) * 128;
  } else {
    m0 = blockIdx.y * 128;
    n0 = blockIdx.x * 128;
  }
  const int wm = (wave >> 1) * 64, wn = (wave & 1) * 64;

  f32x4 acc[4][4] = {};

  auto stage = [&](int b, int kk) {
    short* Asb = SMEM + b * 16384;
    short* Bsb = Asb + 8192;
#pragma unroll
    for (int i = 0; i < 4; ++i) {
      const int p = wave * 256 + i * 64 + lane;
      const int row = p >> 3;
      const int c = (p & 7) ^ (row & 7);
      GLDS16(A  + (size_t)(m0 + row) * K + (kk + c * 8),
             Asb + (size_t)(wave * 256 + i * 64) * 8);
      GLDS16(Bt + (size_t)(n0 + row) * K + (kk + c * 8),
             Bsb + (size_t)(wave * 256 + i * 64) * 8);
    }
  };
  auto compute = [&](int b) {
    const short* Asb = SMEM + b * 16384;
    const short* Bsb = Asb + 8192;
#pragma unroll
    for (int ks = 0; ks < 2; ++ks) {
      bf16x8 af[4], bfr[4];
#pragma unroll
      for (int t = 0; t < 4; ++t) {
        const int ra = wm + t * 16 + l15;
        const int ca = (ks * 4 + quad) ^ (ra & 7);
        af[t] = *(const bf16x8*)(Asb + ra * 64 + ca * 8);
        const int rb = wn + t * 16 + l15;
        const int cb = (ks * 4 + quad) ^ (rb & 7);
        bfr[t] = *(const bf16x8*)(Bsb + rb * 64 + cb * 8);
      }
#pragma unroll
      for (int mt = 0; mt < 4; ++mt)
#pragma unroll
        for (int nt = 0; nt < 4; ++nt)
          acc[mt][nt] = MFMA16(af[mt], bfr[nt], acc[mt][nt], 0, 0, 0);
    }
  };

  stage(0, 0);
  __syncthreads();
  int cur = 0;
  const int NT = K >> 6;
  for (int t = 0; t < NT - 1; ++t) {
    stage(cur ^ 1, (t + 1) * 64);
    compute(cur);
    __syncthreads();
    cur ^= 1;
  }
  compute(cur);

  // --- LDS-bounce epilogue.  acc layout: row=quad*4+reg, col=l15 [m89/m91].
  __syncthreads();
  if constexpr (EPI == 0 || EPI == 1) {
#pragma unroll
    for (int nt = 0; nt < 4; ++nt) {
      const int col = wn + nt * 16 + l15;
      const float bv = bias[n0 + col];
#pragma unroll
      for (int mt = 0; mt < 4; ++mt)
#pragma unroll
        for (int reg = 0; reg < 4; ++reg) {
          const int row = wm + mt * 16 + quad * 4 + reg;
          float v = acc[mt][nt][reg] + bv;
          if constexpr (EPI == 1) v = gelu_f(v);
          const int byte = (row << 8) | ((col << 1) ^ ((row & 7) << 4));
          *(short*)((char*)SMEM + byte) = f2bf(v);
        }
    }
    __syncthreads();
    short* out = (short*)OutP;
#pragma unroll
    for (int i = 0; i < 8; ++i) {
      const int off = i * 4096 + tid * 16;    // logical byte in [128][256B]
      const int row = off >> 8;
      const bf16x8 val =
          *(const bf16x8*)((char*)SMEM + (off ^ ((row & 7) << 4)));
      if constexpr (EPI == 0) {
        // head-major: [win][h][gq][64][32]
        const int colg = n0 + ((off & 255) >> 1);      // global col 0..767
        const int gq = colg >> 8, rem = colg & 255;
        const int hh = rem >> 5, dd = rem & 31;        // dd multiple of 8
        const int grow = m0 + row;
        const int win = grow >> 6, tok = grow & 63;
        *(bf16x8*)(out + ((((size_t)win * 8 + hh) * 3 + gq) << 11)
                       + tok * 32 + dd) = val;
      } else {
        *(bf16x8*)(out + (size_t)(m0 + row) * N + n0 + ((off & 255) >> 1)) = val;
      }
    }
  } else {
    // f32 path in two 64-row halves (32 KB each): Cs_f32[64][128]
    float* out = (float*)OutP;
#pragma unroll
    for (int hh = 0; hh < 2; ++hh) {
      if (hh) __syncthreads();
      if (wm == hh * 64) {
#pragma unroll
        for (int nt = 0; nt < 4; ++nt) {
          const int col = wn + nt * 16 + l15;
          const float bv = bias[n0 + col];
#pragma unroll
          for (int mt = 0; mt < 4; ++mt)
#pragma unroll
            for (int reg = 0; reg < 4; ++reg) {
              const int rloc = mt * 16 + quad * 4 + reg;
              const int byte = (rloc << 9) | ((col << 2) ^ ((rloc & 7) << 4));
              *(float*)((char*)SMEM + byte) = acc[mt][nt][reg] + bv;
            }
        }
      }
      __syncthreads();
#pragma unroll
      for (int i = 0; i < 8; ++i) {
        const int off = i * 4096 + tid * 16;  // logical byte in [64][512B]
        const int rloc = off >> 9;
        f32x4 val = *(const f32x4*)((char*)SMEM + (off ^ ((rloc & 7) << 4)));
        const int colf = (off & 511) >> 2;
        const int grow = m0 + hh * 64 + rloc;
        size_t dst;
        if constexpr (EPI == 2) {
          const int win = grow >> 6, tok = grow & 63;
          const int b = win / 784, wi = win % 784;
          const int wd = wi / 196, wh = (wi / 14) % 14, ww = wi % 14;
          const int tz = tok >> 4, ty = (tok >> 2) & 3, tx = tok & 3;
          const int gd = (wd * 4 + tz + 2) & 15;
          int gh = wh * 4 + ty + 2; if (gh >= 56) gh -= 56;
          int gw = ww * 4 + tx + 2; if (gw >= 56) gw -= 56;
          dst = ((((size_t)b * 16 + gd) * 56 + gh) * 56 + gw) * 256
                + n0 + colf;
        } else {
          dst = (size_t)grow * 256 + n0 + colf;
        }
        const f32x4 r = *(const f32x4*)(resid + dst);
        val = val + r;
        *(f32x4*)(out + dst) = val;
      }
    }
  }
}

// ---------------------------------------------------------------------------
// Windowed attention. grid = 1568*2 blocks; 4 waves, 1 head/wave.
// qkv in head-major layout [win][h][q/k/v][64][32]: Q/K fragment loads are
// fully coalesced (lane l15*64B + quad*16B = contiguous 1KB per wave load).
__global__ __launch_bounds__(256) void attn_k(
    const short* __restrict__ qkv, const float* __restrict__ rpb,
    short* __restrict__ aout) {
  __shared__ short Plds[4 * 64 * 80];
  const int tid = threadIdx.x;
  const int wave = tid >> 6, lane = tid & 63;
  const int quad = lane >> 4, l15 = lane & 15;
  const int win = blockIdx.x >> 1;
  const int h = ((blockIdx.x & 1) << 2) + wave;
  const int wi = win % 784;
  const int wd = wi / 196, wh = (wi / 14) % 14, ww = wi % 14;
  const short* base = qkv + ((((size_t)win * 8 + h) * 3) << 11);

  bf16x8 qf[4], kf[4];
#pragma unroll
  for (int t = 0; t < 4; ++t) {
    qf[t] = *(const bf16x8*)(base + (t * 16 + l15) * 32 + quad * 8);
    kf[t] = *(const bf16x8*)(base + 2048 + (t * 16 + l15) * 32 + quad * 8);
  }
  f32x4 S[4][4] = {};
#pragma unroll
  for (int mt = 0; mt < 4; ++mt)
#pragma unroll
    for (int nt = 0; nt < 4; ++nt)
      S[mt][nt] = MFMA16(qf[mt], kf[nt], S[mt][nt], 0, 0, 0);

  const bool bd = (wd == 3), bh = (wh == 13), bw = (ww == 13);
  const int yc = l15 >> 2, xc = l15 & 3;
  int labc[4];
#pragma unroll
  for (int nt = 0; nt < 4; ++nt) {
    const int rd = bd ? (nt < 2 ? 1 : 2) : 0;
    const int rh = bh ? (yc < 2 ? 1 : 2) : 0;
    const int rw = bw ? (xc < 2 ? 1 : 2) : 0;
    labc[nt] = rd * 9 + rh * 3 + rw;
  }
  const float scale = 0.17677669529663687f;   // 32^-0.5
#pragma unroll
  for (int mt = 0; mt < 4; ++mt) {
    const int rdr = bd ? (mt < 2 ? 1 : 2) : 0;
    const int rhr = bh ? (quad < 2 ? 1 : 2) : 0;
#pragma unroll
    for (int reg = 0; reg < 4; ++reg) {
      const int rwr = bw ? (reg < 2 ? 1 : 2) : 0;
      const int labr = rdr * 9 + rhr * 3 + rwr;
      float sc[4];
#pragma unroll
      for (int nt = 0; nt < 4; ++nt) {
        const int rpi = (mt - nt + 3) * 49 + (quad - yc + 3) * 7 + (reg - xc + 3);
        const float bias = rpb[rpi * 8 + h];
        const float mv = (labr == labc[nt]) ? 0.f : -100.f;
        sc[nt] = S[mt][nt][reg] * scale + bias + mv;
      }
      float mx = fmaxf(fmaxf(sc[0], sc[1]), fmaxf(sc[2], sc[3]));
      mx = fmaxf(mx, __shfl_xor(mx, 1));
      mx = fmaxf(mx, __shfl_xor(mx, 2));
      mx = fmaxf(mx, __shfl_xor(mx, 4));
      mx = fmaxf(mx, __shfl_xor(mx, 8));
      float p[4], sum = 0.f;
#pragma unroll
      for (int nt = 0; nt < 4; ++nt) { p[nt] = __expf(sc[nt] - mx); sum += p[nt]; }
      sum += __shfl_xor(sum, 1);
      sum += __shfl_xor(sum, 2);
      sum += __shfl_xor(sum, 4);
      sum += __shfl_xor(sum, 8);
      const float inv = 1.f / sum;
      const int r = mt * 16 + quad * 4 + reg;
#pragma unroll
      for (int nt = 0; nt < 4; ++nt)
        Plds[(wave * 64 + r) * 80 + nt * 16 + l15] = f2bf(p[nt] * inv);
    }
  }

  bf16x8 vf[2][2];
#pragma unroll
  for (int kt = 0; kt < 2; ++kt)
#pragma unroll
    for (int n2 = 0; n2 < 2; ++n2)
#pragma unroll
      for (int j = 0; j < 8; ++j)
        vf[kt][n2][j] =
            base[4096 + (kt * 32 + quad * 8 + j) * 32 + n2 * 16 + l15];

  f32x4 O[4][2] = {};
#pragma unroll
  for (int mt = 0; mt < 4; ++mt) {
    const short* pr = &Plds[(wave * 64 + mt * 16 + l15) * 80 + quad * 8];
    const bf16x8 pa0 = *(const bf16x8*)pr;
    const bf16x8 pa1 = *(const bf16x8*)(pr + 32);
#pragma unroll
    for (int n2 = 0; n2 < 2; ++n2) {
      O[mt][n2] = MFMA16(pa0, vf[0][n2], O[mt][n2], 0, 0, 0);
      O[mt][n2] = MFMA16(pa1, vf[1][n2], O[mt][n2], 0, 0, 0);
    }
  }
#pragma unroll
  for (int mt = 0; mt < 4; ++mt)
#pragma unroll
    for (int n2 = 0; n2 < 2; ++n2)
#pragma unroll
      for (int reg = 0; reg < 4; ++reg) {
        const int tok = mt * 16 + quad * 4 + reg;
        aout[((size_t)win * 64 + tok) * 256 + h * 32 + n2 * 16 + l15] =
            f2bf(O[mt][n2][reg]);
      }
}

// ---------------------------------------------------------------------------
extern "C" void kernel_launch(void* const* d_in, const int* in_sizes, int n_in,
                              void* d_out, int out_size, void* d_ws,
                              size_t ws_size, hipStream_t stream) {
  const float* x      = (const float*)d_in[0];
  const float* n1g    = (const float*)d_in[1];
  const float* n1b    = (const float*)d_in[2];
  const float* qkv_w  = (const float*)d_in[3];
  const float* qkv_b  = (const float*)d_in[4];
  const float* proj_w = (const float*)d_in[5];
  const float* proj_b = (const float*)d_in[6];
  const float* rpb    = (const float*)d_in[7];
  const float* n2g    = (const float*)d_in[8];
  const float* n2b    = (const float*)d_in[9];
  const float* fc1_w  = (const float*)d_in[10];
  const float* fc1_b  = (const float*)d_in[11];
  const float* fc2_w  = (const float*)d_in[12];
  const float* fc2_b  = (const float*)d_in[13];

  char* ws = (char*)d_ws;
  short* wt_qkv  = (short*)(ws + 0);          //     393,216 B
  short* wt_proj = (short*)(ws + 393216);     //     131,072 B
  short* wt_fc1  = (short*)(ws + 524288);     //     524,288 B
  short* wt_fc2  = (short*)(ws + 1048576);    //     524,288 B
  short* bufS    = (short*)(ws + 1572864);    //  51,380,224 B (xw/ao/yn)
  short* bufL    = (short*)(ws + 52953088);   // 205,520,896 B (qkv/h1)
  // total 258,473,984 B
  float* x1      = (float*)d_out;             // x1 lives in d_out (f32)

  transpose_all_k<<<3072, 256, 0, stream>>>(qkv_w, proj_w, fc1_w, fc2_w,
                                            wt_qkv, wt_proj, wt_fc1, wt_fc2);
  ln1_part_k<<<25088, 256, 0, stream>>>(x, n1g, n1b, bufS);
  gemm_k<0, 0><<<dim3(6, 784), 256, 0, stream>>>(bufS, wt_qkv, qkv_b, nullptr,
                                                 bufL, 768, 256);
  attn_k<<<3136, 256, 0, stream>>>(bufL, rpb, bufS);
  gemm_k<2, 0><<<dim3(2, 784), 256, 0, stream>>>(bufS, wt_proj, proj_b, x,
                                                 x1, 256, 256);
  ln2_k<<<25088, 256, 0, stream>>>(x1, n2g, n2b, bufS);
  gemm_k<1, 1><<<dim3(8, 784), 256, 0, stream>>>(bufS, wt_fc1, fc1_b, nullptr,
                                                 bufL, 1024, 256);
  gemm_k<3, 0><<<dim3(2, 784), 256, 0, stream>>>(bufL, wt_fc2, fc2_b, x1,
                                                 x1, 256, 1024);
}